// Round 6
// baseline (19540.868 us; speedup 1.0000x reference)
//
#include <hip/hip_runtime.h>
#include <hip/hip_bf16.h>
#include <stdint.h>

#define SEQ   512
#define BATCH 256
#define EMBD  256
#define HID   512
#define OUTD  4

typedef float  f32x4 __attribute__((ext_vector_type(4)));
typedef short  s16x8 __attribute__((ext_vector_type(8)));
typedef __bf16 bf16x8 __attribute__((ext_vector_type(8)));

static __device__ __forceinline__ short f2bf(float f) {
    union { float f; uint32_t u; } v; v.f = f;
    uint32_t u = v.u;
    u += 0x7fffu + ((u >> 16) & 1u);      // round-to-nearest-even
    return (short)(u >> 16);
}
static __device__ __forceinline__ float bf2f(short s) {
    union { uint32_t u; float f; } v;
    v.u = ((uint32_t)(uint16_t)s) << 16;
    return v.f;
}

static __device__ __forceinline__ f32x4 mfma_bf16(s16x8 a, s16x8 b, f32x4 c) {
    return __builtin_amdgcn_mfma_f32_16x16x32_bf16(
        __builtin_bit_cast(bf16x8, a), __builtin_bit_cast(bf16x8, b), c, 0, 0, 0);
}

// Agent-coherent (L1/L2-bypassing) accesses — validated in round 2.
static __device__ __forceinline__ s16x8 load_coherent_b128(const void* p) {
    s16x8 r;
    asm volatile("global_load_dwordx4 %0, %1, off sc0 sc1"
                 : "=v"(r) : "v"(p) : "memory");
    return r;
}
static __device__ __forceinline__ void store_coherent_b128(void* p, s16x8 v) {
    asm volatile("global_store_dwordx4 %0, %1, off sc0 sc1"
                 :: "v"(p), "v"(v) : "memory");
}
static __device__ __forceinline__ void wait_vm0() {
    asm volatile("s_waitcnt vmcnt(0)" ::: "memory");
    __builtin_amdgcn_sched_barrier(0);   // rule #18
}

// xp store/load: f32 or bf16 (workspace-size dependent)
static __device__ __forceinline__ void  xp_store(float* p, float v) { *p = v; }
static __device__ __forceinline__ void  xp_store(short* p, float v) { *p = f2bf(v); }
static __device__ __forceinline__ float xp_load(const float* p)     { return *p; }
static __device__ __forceinline__ float xp_load(const short* p)     { return bf2f(*p); }

// ---------------------------------------------------------------------------
// Kernel 1: xp = emb[text] @ W_ih^T + b_ih + b_hh   (round-2-validated, exact)
// ---------------------------------------------------------------------------
template <typename XT>
__global__ __launch_bounds__(512, 1)
void xproj_kernel(const int* __restrict__ text, const float* __restrict__ emb,
                  const float* __restrict__ W_ih, const float* __restrict__ b_ih,
                  const float* __restrict__ b_hh, XT* __restrict__ xp) {
    extern __shared__ char lds[];
    char* As = lds;             // [128][256] bf16, swizzled
    char* Bs = lds + 65536;     // [128][256] bf16, swizzled

    const int t    = threadIdx.x;
    const int row0 = blockIdx.x * 128;
    const int col0 = blockIdx.y * 128;

    {   // stage A: gathered embedding rows, f32 -> bf16
        const int r   = t >> 2;
        const int kc  = (t & 3) * 64;
        const int tok = text[row0 + r];
        const float* src = emb + (size_t)tok * EMBD + kc;
        #pragma unroll
        for (int u = 0; u < 64; u += 8) {
            f32x4 x0 = *(const f32x4*)(src + u);
            f32x4 x1 = *(const f32x4*)(src + u + 4);
            s16x8 pk;
            pk[0]=f2bf(x0.x); pk[1]=f2bf(x0.y); pk[2]=f2bf(x0.z); pk[3]=f2bf(x0.w);
            pk[4]=f2bf(x1.x); pk[5]=f2bf(x1.y); pk[6]=f2bf(x1.z); pk[7]=f2bf(x1.w);
            int byte = (r * 512 + (kc + u) * 2) ^ ((r & 7) << 4);
            *(s16x8*)(As + byte) = pk;
        }
    }
    {   // stage B: W_ih slice
        const int c  = t >> 2;
        const int kc = (t & 3) * 64;
        const float* src = W_ih + (size_t)(col0 + c) * EMBD + kc;
        #pragma unroll
        for (int u = 0; u < 64; u += 8) {
            f32x4 x0 = *(const f32x4*)(src + u);
            f32x4 x1 = *(const f32x4*)(src + u + 4);
            s16x8 pk;
            pk[0]=f2bf(x0.x); pk[1]=f2bf(x0.y); pk[2]=f2bf(x0.z); pk[3]=f2bf(x0.w);
            pk[4]=f2bf(x1.x); pk[5]=f2bf(x1.y); pk[6]=f2bf(x1.z); pk[7]=f2bf(x1.w);
            int byte = (c * 512 + (kc + u) * 2) ^ ((c & 7) << 4);
            *(s16x8*)(Bs + byte) = pk;
        }
    }
    __syncthreads();

    const int lane = t & 63;
    const int w    = t >> 6;
    const int wm   = w >> 2;
    const int wn   = w & 3;
    const int lr   = lane & 15;
    const int lk   = (lane >> 4) * 8;

    f32x4 acc[4][2] = {};
    #pragma unroll
    for (int kk = 0; kk < 8; ++kk) {
        s16x8 a[4], b[2];
        #pragma unroll
        for (int mt = 0; mt < 4; ++mt) {
            int r = wm * 64 + mt * 16 + lr;
            int byte = (r * 512 + (kk * 32 + lk) * 2) ^ ((r & 7) << 4);
            a[mt] = *(const s16x8*)(As + byte);
        }
        #pragma unroll
        for (int nt = 0; nt < 2; ++nt) {
            int c = wn * 32 + nt * 16 + lr;
            int byte = (c * 512 + (kk * 32 + lk) * 2) ^ ((c & 7) << 4);
            b[nt] = *(const s16x8*)(Bs + byte);
        }
        #pragma unroll
        for (int mt = 0; mt < 4; ++mt)
            #pragma unroll
            for (int nt = 0; nt < 2; ++nt)
                acc[mt][nt] = mfma_bf16(a[mt], b[nt], acc[mt][nt]);
    }

    #pragma unroll
    for (int nt = 0; nt < 2; ++nt) {
        const int c = col0 + wn * 32 + nt * 16 + lr;
        const float bias = b_ih[c] + b_hh[c];
        #pragma unroll
        for (int mt = 0; mt < 4; ++mt) {
            #pragma unroll
            for (int r4 = 0; r4 < 4; ++r4) {
                const int rr = row0 + wm * 64 + mt * 16 + (lane >> 4) * 4 + r4;
                xp_store(xp + (size_t)rr * HID + c, acc[mt][nt][r4] + bias);
            }
        }
    }
}

// ---------------------------------------------------------------------------
// Kernel 2: round-2-validated recurrence (cross-WG exchange via sc0 sc1 L3
// bypass + relaxed agent atomics). Writes d_out. EXACT copy of the passing
// round-2 kernel.
// ---------------------------------------------------------------------------
template <typename XT>
__global__ __launch_bounds__(256, 1)
void rnn_kernel(const float* __restrict__ W_hh, const XT* __restrict__ xp,
                const float* __restrict__ fc_w, const float* __restrict__ fc_b,
                short* __restrict__ hbuf, unsigned int* __restrict__ bar,
                float* __restrict__ out) {
    extern __shared__ char lds[];                 // W slice [128][512] bf16 swizzled
    short* hstage = (short*)(lds + 131072);       // [16][128] bf16 transpose buffer

    const int bid  = blockIdx.x;                       // 0..63
    const int gi   = (bid & 7) + ((bid >> 5) << 3);    // row group 0..15
    const int gj   = (bid >> 3) & 3;                   // col slice 0..3
    const int t    = threadIdx.x;
    const int lane = t & 63;
    const int w    = t >> 6;                           // 0..3 waves
    const int row0 = gi * 16;
    const int col0 = gj * 128;

    {   // stage W_hh slice (once), f32 -> bf16
        const int c  = t >> 1;
        const int k0 = (t & 1) * 256;
        const float* src = W_hh + (size_t)(col0 + c) * HID + k0;
        #pragma unroll 4
        for (int u = 0; u < 256; u += 8) {
            f32x4 x0 = *(const f32x4*)(src + u);
            f32x4 x1 = *(const f32x4*)(src + u + 4);
            s16x8 pk;
            pk[0]=f2bf(x0.x); pk[1]=f2bf(x0.y); pk[2]=f2bf(x0.z); pk[3]=f2bf(x0.w);
            pk[4]=f2bf(x1.x); pk[5]=f2bf(x1.y); pk[6]=f2bf(x1.z); pk[7]=f2bf(x1.w);
            int byte = (c * 1024 + (k0 + u) * 2) ^ ((c & 7) << 4);
            *(s16x8*)(lds + byte) = pk;
        }
    }
    __syncthreads();

    const int lr    = lane & 15;
    const int lkb   = (lane >> 4) * 16;
    const int arow  = row0 + lr;
    const int crow0 = row0 + (lane >> 4) * 4;
    unsigned int* mybar = bar + gi;

    int p = 0;
    for (int s = 0; s < SEQ; ++s) {
        f32x4 acc[2];
        #pragma unroll
        for (int nt = 0; nt < 2; ++nt) {
            const int c = col0 + w * 32 + nt * 16 + lr;
            const XT* xs = xp + ((size_t)s * BATCH + crow0) * HID + c;
            #pragma unroll
            for (int r = 0; r < 4; ++r) acc[nt][r] = xp_load(xs + (size_t)r * HID);
        }

        if (s > 0) {
            if (t == 0) {
                const unsigned int target = 4u * (unsigned int)s;
                int guard = 0;
                while (__hip_atomic_load(mybar, __ATOMIC_RELAXED,
                                         __HIP_MEMORY_SCOPE_AGENT) < target) {
                    __builtin_amdgcn_s_sleep(1);
                    if (++guard > (1 << 27)) break;
                }
            }
            __syncthreads();
        }

        const short* hb   = hbuf + (size_t)p * (BATCH * HID);
        const char*  hrow = (const char*)(hb + (size_t)arow * HID);
        s16x8 areg[16];
        #pragma unroll
        for (int kk = 0; kk < 16; ++kk)
            areg[kk] = load_coherent_b128(hrow + kk * 64 + lkb);
        wait_vm0();

        const int cl0 = w * 32 + lr;
        const int cl1 = cl0 + 16;
        #pragma unroll
        for (int kk = 0; kk < 16; ++kk) {
            const int b0b = (cl0 * 1024 + kk * 64 + lkb) ^ ((cl0 & 7) << 4);
            const int b1b = (cl1 * 1024 + kk * 64 + lkb) ^ ((cl1 & 7) << 4);
            const s16x8 b0v = *(const s16x8*)(lds + b0b);
            const s16x8 b1v = *(const s16x8*)(lds + b1b);
            acc[0] = mfma_bf16(areg[kk], b0v, acc[0]);
            acc[1] = mfma_bf16(areg[kk], b1v, acc[1]);
        }

        #pragma unroll
        for (int nt = 0; nt < 2; ++nt) {
            const int cl = w * 32 + nt * 16 + lr;
            #pragma unroll
            for (int r = 0; r < 4; ++r)
                hstage[((crow0 - row0) + r) * 128 + cl] = f2bf(tanhf(acc[nt][r]));
        }
        __syncthreads();

        {
            const int rr = t >> 4, c8 = (t & 15) * 8;
            s16x8 v = *(const s16x8*)(hstage + rr * 128 + c8);
            short* hn = hbuf + (size_t)(p ^ 1) * (BATCH * HID)
                             + (size_t)(row0 + rr) * HID + (col0 + c8);
            store_coherent_b128(hn, v);
        }
        __syncthreads();

        if (t == 0)
            __hip_atomic_fetch_add(mybar, 1u, __ATOMIC_RELAXED,
                                   __HIP_MEMORY_SCOPE_AGENT);
        p ^= 1;
    }

    if (gj == 0) {
        if (t == 0) {
            int guard = 0;
            while (__hip_atomic_load(mybar, __ATOMIC_RELAXED,
                                     __HIP_MEMORY_SCOPE_AGENT) < 4u * SEQ) {
                __builtin_amdgcn_s_sleep(1);
                if (++guard > (1 << 27)) break;
            }
        }
        __syncthreads();

        const int i  = t >> 2;
        const int q  = t & 3;
        const int bl = i >> 2;
        const int o  = i & 3;
        const short* hb = hbuf + (size_t)p * (BATCH * HID)
                               + (size_t)(row0 + bl) * HID + q * 128;
        s16x8 hv[16];
        #pragma unroll
        for (int kk = 0; kk < 16; ++kk)
            hv[kk] = load_coherent_b128((const char*)hb + kk * 16);
        wait_vm0();
        float sum = 0.f;
        #pragma unroll
        for (int kk = 0; kk < 16; ++kk)
            #pragma unroll
            for (int j = 0; j < 8; ++j)
                sum += bf2f(hv[kk][j]) * fc_w[o * HID + q * 128 + kk * 8 + j];
        sum += __shfl_xor(sum, 1);
        sum += __shfl_xor(sum, 2);
        if (q == 0)
            out[(row0 + bl) * OUTD + o] = sum + fc_b[o];
    }
}

// ---------------------------------------------------------------------------
// PROBE: the round-5 self-contained kernel, writing NOTHING to d_out.
// Recomputes the recurrence (16 WGs x 512 thr, W in LDS+regs), then
// self-checks its final h vs the validated kernel's h (href = hbuf buffer 0)
// and encodes the verdict in its DURATION:
//   ~1 unit  (~5-6 ms)  : ran, h finite and matches (|diff| <= 0.1)
//   ~3 units (~17 ms)   : ran, h contains NaN
//   ~6 units (~34 ms)   : ran, h finite but mismatched
//   dispatch absent     : 160KB-LDS launch failed
// ---------------------------------------------------------------------------
template <typename XT>
__global__ __launch_bounds__(512, 2)
void rnn_probe(const float* __restrict__ W_hh, const XT* __restrict__ xp,
               const short* __restrict__ href) {
    extern __shared__ char lds[];
    char* Wl = lds;                 // [128 cols][512 k] bf16, swz: ^((c&7)<<4)
    char* hB = lds + 131072;        // two h buffers [16][512] bf16, swz by row

    const int t    = threadIdx.x;
    const int lane = t & 63;
    const int w    = t >> 6;        // 0..7
    const int lr   = lane & 15;
    const int hi   = lane >> 4;     // 0..3
    const int row0 = blockIdx.x * 16;

    {   // stage W cols 0..127 into LDS, f32 -> bf16
        const int c  = t >> 2;
        const int k0 = (t & 3) * 128;
        const float* src = W_hh + (size_t)c * HID + k0;
        #pragma unroll 4
        for (int u = 0; u < 128; u += 8) {
            f32x4 x0 = *(const f32x4*)(src + u);
            f32x4 x1 = *(const f32x4*)(src + u + 4);
            s16x8 pk;
            pk[0]=f2bf(x0.x); pk[1]=f2bf(x0.y); pk[2]=f2bf(x0.z); pk[3]=f2bf(x0.w);
            pk[4]=f2bf(x1.x); pk[5]=f2bf(x1.y); pk[6]=f2bf(x1.z); pk[7]=f2bf(x1.w);
            int byte = (c * 1024 + (k0 + u) * 2) ^ ((c & 7) << 4);
            *(s16x8*)(Wl + byte) = pk;
        }
    }
    {   // zero BOTH h buffers
        s16x8 z;
        #pragma unroll
        for (int i = 0; i < 8; ++i) z[i] = 0;
        *(s16x8*)(hB + t * 32) = z;
        *(s16x8*)(hB + 16384 + t * 32) = z;
    }
    // stage W cols 128..511 into registers
    s16x8 wr0[16], wr1[16], wr2[16];
    {
        const float* s0 = W_hh + (size_t)(128 + w * 48 +  0 + lr) * HID + hi * 8;
        const float* s1 = W_hh + (size_t)(128 + w * 48 + 16 + lr) * HID + hi * 8;
        const float* s2 = W_hh + (size_t)(128 + w * 48 + 32 + lr) * HID + hi * 8;
        #pragma unroll
        for (int kk = 0; kk < 16; ++kk) {
            f32x4 a0 = *(const f32x4*)(s0 + kk * 32);
            f32x4 a1 = *(const f32x4*)(s0 + kk * 32 + 4);
            f32x4 b0 = *(const f32x4*)(s1 + kk * 32);
            f32x4 b1 = *(const f32x4*)(s1 + kk * 32 + 4);
            f32x4 c0 = *(const f32x4*)(s2 + kk * 32);
            f32x4 c1 = *(const f32x4*)(s2 + kk * 32 + 4);
            s16x8 p;
            p[0]=f2bf(a0.x); p[1]=f2bf(a0.y); p[2]=f2bf(a0.z); p[3]=f2bf(a0.w);
            p[4]=f2bf(a1.x); p[5]=f2bf(a1.y); p[6]=f2bf(a1.z); p[7]=f2bf(a1.w);
            wr0[kk] = p;
            p[0]=f2bf(b0.x); p[1]=f2bf(b0.y); p[2]=f2bf(b0.z); p[3]=f2bf(b0.w);
            p[4]=f2bf(b1.x); p[5]=f2bf(b1.y); p[6]=f2bf(b1.z); p[7]=f2bf(b1.w);
            wr1[kk] = p;
            p[0]=f2bf(c0.x); p[1]=f2bf(c0.y); p[2]=f2bf(c0.z); p[3]=f2bf(c0.w);
            p[4]=f2bf(c1.x); p[5]=f2bf(c1.y); p[6]=f2bf(c1.z); p[7]=f2bf(c1.w);
            wr2[kk] = p;
        }
    }
    __syncthreads();

    const int crow = hi * 4;
    const int colL = w * 16 + lr;
    const int colR = 128 + w * 48 + lr;
    const int swzL = (lr & 7) << 4;

    int p = 0;
    #pragma unroll 1
    for (int s = 0; s < SEQ; ++s) {
        const char* hc = hB + p * 16384;
        char*       hn = hB + (p ^ 1) * 16384;

        f32x4 xpv[4];
        {
            const XT* xs = xp + ((size_t)s * BATCH + row0 + crow) * HID;
            #pragma unroll
            for (int r = 0; r < 4; ++r) {
                xpv[0][r] = xp_load(xs + (size_t)r * HID + colL);
                xpv[1][r] = xp_load(xs + (size_t)r * HID + colR);
                xpv[2][r] = xp_load(xs + (size_t)r * HID + colR + 16);
                xpv[3][r] = xp_load(xs + (size_t)r * HID + colR + 32);
            }
        }

        f32x4 acc[4] = {};
        #pragma unroll
        for (int kk = 0; kk < 16; ++kk) {
            const int kb = kk * 64 + hi * 16;
            const s16x8 a  = *(const s16x8*)(hc + ((lr * 1024 + kb) ^ swzL));
            const s16x8 bl = *(const s16x8*)(Wl + ((colL * 1024 + kb) ^ swzL));
            acc[0] = mfma_bf16(a, bl,      acc[0]);
            acc[1] = mfma_bf16(a, wr0[kk], acc[1]);
            acc[2] = mfma_bf16(a, wr1[kk], acc[2]);
            acc[3] = mfma_bf16(a, wr2[kk], acc[3]);
        }

        #pragma unroll
        for (int ti = 0; ti < 4; ++ti) {
            const int c = (ti == 0) ? colL : (colR + (ti - 1) * 16);
            #pragma unroll
            for (int r = 0; r < 4; ++r) {
                const float hv = tanhf(acc[ti][r] + xpv[ti][r]);
                const int rr = crow + r;
                *(short*)(hn + ((rr * 1024 + c * 2) ^ ((rr & 7) << 4))) = f2bf(hv);
            }
        }
        __syncthreads();
        p ^= 1;
    }

    // ---- self-check + coded spin (p == 0 after 512 steps; buffer 1 free) ----
    {
        int* flg = (int*)(hB + 16384);
        if (t == 0) { flg[0] = 0; flg[1] = 0; }
        __syncthreads();
        const char* hf = hB;                 // final h = buffer 0
        const int rr = t >> 5;               // 0..15
        const int c0 = (t & 31) * 16;        // 16 cols per thread
        const int fswz = (rr & 7) << 4;
        int bad_nan = 0, bad_mis = 0;
        #pragma unroll 4
        for (int j = 0; j < 16; ++j) {
            const int c = c0 + j;
            const float a = bf2f(*(const short*)(hf + ((rr * 1024 + c * 2) ^ fswz)));
            const float b = bf2f(href[(size_t)(row0 + rr) * HID + c]);
            if (!(a == a)) bad_nan = 1;
            else if (!(fabsf(a - b) <= 0.10f)) bad_mis = 1;
        }
        if (bad_nan) flg[0] = 1;
        if (bad_mis) flg[1] = 1;
        __syncthreads();
        const int units = flg[0] ? 3 : (flg[1] ? 6 : 1);
        for (int i = 0; i < units * 100000; ++i)
            asm volatile("s_sleep 2" ::: "memory");
    }
}

// ---------------------------------------------------------------------------
extern "C" void kernel_launch(void* const* d_in, const int* in_sizes, int n_in,
                              void* d_out, int out_size, void* d_ws, size_t ws_size,
                              hipStream_t stream) {
    (void)in_sizes; (void)n_in; (void)out_size;
    const int*   text = (const int*)  d_in[0];
    const float* emb  = (const float*)d_in[1];
    const float* W_ih = (const float*)d_in[2];
    const float* W_hh = (const float*)d_in[3];
    const float* b_ih = (const float*)d_in[4];
    const float* b_hh = (const float*)d_in[5];
    const float* fc_w = (const float*)d_in[6];
    const float* fc_b = (const float*)d_in[7];
    float* out = (float*)d_out;

    char* ws = (char*)d_ws;
    short*        hbuf = (short*)ws;                        // 2*256*512*2 = 512 KB
    unsigned int* bar  = (unsigned int*)(ws + (512 << 10)); // 16 counters
    void*         xpbf = (void*)(ws + (1 << 20));

    const size_t base     = (size_t)1 << 20;
    const size_t xp_elems = (size_t)SEQ * BATCH * HID;
    const bool use_f32  = ws_size >= base + xp_elems * 4;
    const bool use_bf16 = !use_f32 && ws_size >= base + xp_elems * 2;

    // zero h0 + barrier counters (every call: deterministic)
    hipMemsetAsync(ws, 0, (512 << 10) + 4096, stream);

    if (use_f32) {
        hipFuncSetAttribute(reinterpret_cast<const void*>(&xproj_kernel<float>),
                            hipFuncAttributeMaxDynamicSharedMemorySize, 131072);
        hipFuncSetAttribute(reinterpret_cast<const void*>(&rnn_kernel<float>),
                            hipFuncAttributeMaxDynamicSharedMemorySize, 135168);
        hipFuncSetAttribute(reinterpret_cast<const void*>(&rnn_probe<float>),
                            hipFuncAttributeMaxDynamicSharedMemorySize, 163840);
        xproj_kernel<float><<<dim3(1024, 4, 1), 512, 131072, stream>>>(
            text, emb, W_ih, b_ih, b_hh, (float*)xpbf);
        rnn_kernel<float><<<64, 256, 135168, stream>>>(
            W_hh, (const float*)xpbf, fc_w, fc_b, hbuf, bar, out);
        rnn_probe<float><<<16, 512, 163840, stream>>>(
            W_hh, (const float*)xpbf, hbuf);
    } else if (use_bf16) {
        hipFuncSetAttribute(reinterpret_cast<const void*>(&xproj_kernel<short>),
                            hipFuncAttributeMaxDynamicSharedMemorySize, 131072);
        hipFuncSetAttribute(reinterpret_cast<const void*>(&rnn_kernel<short>),
                            hipFuncAttributeMaxDynamicSharedMemorySize, 135168);
        hipFuncSetAttribute(reinterpret_cast<const void*>(&rnn_probe<short>),
                            hipFuncAttributeMaxDynamicSharedMemorySize, 163840);
        xproj_kernel<short><<<dim3(1024, 4, 1), 512, 131072, stream>>>(
            text, emb, W_ih, b_ih, b_hh, (short*)xpbf);
        rnn_kernel<short><<<64, 256, 135168, stream>>>(
            W_hh, (const short*)xpbf, fc_w, fc_b, hbuf, bar, out);
        rnn_probe<short><<<16, 512, 163840, stream>>>(
            W_hh, (const short*)xpbf, hbuf);
    }
    // else: workspace too small — no launch (signals via bench).
}

// Round 7
// 2273.273 us; speedup vs baseline: 8.5959x; 8.5959x over previous
//
#include <hip/hip_runtime.h>
#include <hip/hip_bf16.h>
#include <stdint.h>

#define SEQ   512
#define BATCH 256
#define EMBD  256
#define HID   512
#define OUTD  4

typedef float  f32x4 __attribute__((ext_vector_type(4)));
typedef short  s16x8 __attribute__((ext_vector_type(8)));
typedef __bf16 bf16x8 __attribute__((ext_vector_type(8)));

static __device__ __forceinline__ short f2bf(float f) {
    union { float f; uint32_t u; } v; v.f = f;
    uint32_t u = v.u;
    u += 0x7fffu + ((u >> 16) & 1u);      // round-to-nearest-even
    return (short)(u >> 16);
}
static __device__ __forceinline__ float bf2f(short s) {
    union { uint32_t u; float f; } v;
    v.u = ((uint32_t)(uint16_t)s) << 16;
    return v.f;
}

static __device__ __forceinline__ f32x4 mfma_bf16(s16x8 a, s16x8 b, f32x4 c) {
    return __builtin_amdgcn_mfma_f32_16x16x32_bf16(
        __builtin_bit_cast(bf16x8, a), __builtin_bit_cast(bf16x8, b), c, 0, 0, 0);
}

// Agent-coherent (L1/L2-bypassing) accesses — validated in round 2.
static __device__ __forceinline__ s16x8 load_coherent_b128(const void* p) {
    s16x8 r;
    asm volatile("global_load_dwordx4 %0, %1, off sc0 sc1"
                 : "=v"(r) : "v"(p) : "memory");
    return r;
}
static __device__ __forceinline__ void store_coherent_b128(void* p, s16x8 v) {
    asm volatile("global_store_dwordx4 %0, %1, off sc0 sc1"
                 :: "v"(p), "v"(v) : "memory");
}
static __device__ __forceinline__ void wait_vm0() {
    asm volatile("s_waitcnt vmcnt(0)" ::: "memory");
    __builtin_amdgcn_sched_barrier(0);   // rule #18
}
static __device__ __forceinline__ void spin_units(int units) {
    // ~1 ms per unit: s_sleep 8 ~ 512 clk @2.4GHz ~ 0.213us; 4700 iters ~ 1ms
    for (int i = 0; i < units * 4700; ++i)
        asm volatile("s_sleep 8" ::: "memory");
}

// xp store/load: f32 or bf16 (workspace-size dependent)
static __device__ __forceinline__ void  xp_store(float* p, float v) { *p = v; }
static __device__ __forceinline__ void  xp_store(short* p, float v) { *p = f2bf(v); }
static __device__ __forceinline__ float xp_load(const float* p)     { return *p; }
static __device__ __forceinline__ float xp_load(const short* p)     { return bf2f(*p); }

// ---------------------------------------------------------------------------
// Kernel 1: xp = emb[text] @ W_ih^T + b_ih + b_hh   (round-2-validated)
// ---------------------------------------------------------------------------
template <typename XT>
__global__ __launch_bounds__(512, 1)
void xproj_kernel(const int* __restrict__ text, const float* __restrict__ emb,
                  const float* __restrict__ W_ih, const float* __restrict__ b_ih,
                  const float* __restrict__ b_hh, XT* __restrict__ xp) {
    extern __shared__ char lds[];
    char* As = lds;
    char* Bs = lds + 65536;

    const int t    = threadIdx.x;
    const int row0 = blockIdx.x * 128;
    const int col0 = blockIdx.y * 128;

    {
        const int r   = t >> 2;
        const int kc  = (t & 3) * 64;
        const int tok = text[row0 + r];
        const float* src = emb + (size_t)tok * EMBD + kc;
        #pragma unroll
        for (int u = 0; u < 64; u += 8) {
            f32x4 x0 = *(const f32x4*)(src + u);
            f32x4 x1 = *(const f32x4*)(src + u + 4);
            s16x8 pk;
            pk[0]=f2bf(x0.x); pk[1]=f2bf(x0.y); pk[2]=f2bf(x0.z); pk[3]=f2bf(x0.w);
            pk[4]=f2bf(x1.x); pk[5]=f2bf(x1.y); pk[6]=f2bf(x1.z); pk[7]=f2bf(x1.w);
            int byte = (r * 512 + (kc + u) * 2) ^ ((r & 7) << 4);
            *(s16x8*)(As + byte) = pk;
        }
    }
    {
        const int c  = t >> 2;
        const int kc = (t & 3) * 64;
        const float* src = W_ih + (size_t)(col0 + c) * EMBD + kc;
        #pragma unroll
        for (int u = 0; u < 64; u += 8) {
            f32x4 x0 = *(const f32x4*)(src + u);
            f32x4 x1 = *(const f32x4*)(src + u + 4);
            s16x8 pk;
            pk[0]=f2bf(x0.x); pk[1]=f2bf(x0.y); pk[2]=f2bf(x0.z); pk[3]=f2bf(x0.w);
            pk[4]=f2bf(x1.x); pk[5]=f2bf(x1.y); pk[6]=f2bf(x1.z); pk[7]=f2bf(x1.w);
            int byte = (c * 512 + (kc + u) * 2) ^ ((c & 7) << 4);
            *(s16x8*)(Bs + byte) = pk;
        }
    }
    __syncthreads();

    const int lane = t & 63;
    const int w    = t >> 6;
    const int wm   = w >> 2;
    const int wn   = w & 3;
    const int lr   = lane & 15;
    const int lk   = (lane >> 4) * 8;

    f32x4 acc[4][2] = {};
    #pragma unroll
    for (int kk = 0; kk < 8; ++kk) {
        s16x8 a[4], b[2];
        #pragma unroll
        for (int mt = 0; mt < 4; ++mt) {
            int r = wm * 64 + mt * 16 + lr;
            int byte = (r * 512 + (kk * 32 + lk) * 2) ^ ((r & 7) << 4);
            a[mt] = *(const s16x8*)(As + byte);
        }
        #pragma unroll
        for (int nt = 0; nt < 2; ++nt) {
            int c = wn * 32 + nt * 16 + lr;
            int byte = (c * 512 + (kk * 32 + lk) * 2) ^ ((c & 7) << 4);
            b[nt] = *(const s16x8*)(Bs + byte);
        }
        #pragma unroll
        for (int mt = 0; mt < 4; ++mt)
            #pragma unroll
            for (int nt = 0; nt < 2; ++nt)
                acc[mt][nt] = mfma_bf16(a[mt], b[nt], acc[mt][nt]);
    }

    #pragma unroll
    for (int nt = 0; nt < 2; ++nt) {
        const int c = col0 + wn * 32 + nt * 16 + lr;
        const float bias = b_ih[c] + b_hh[c];
        #pragma unroll
        for (int mt = 0; mt < 4; ++mt) {
            #pragma unroll
            for (int r4 = 0; r4 < 4; ++r4) {
                const int rr = row0 + wm * 64 + mt * 16 + (lane >> 4) * 4 + r4;
                xp_store(xp + (size_t)rr * HID + c, acc[mt][nt][r4] + bias);
            }
        }
    }
}

// ---------------------------------------------------------------------------
// W prep: bf16 image of W_hh (identical f2bf bits to all staged copies).
// ---------------------------------------------------------------------------
__global__ void wprep_kernel(const float* __restrict__ W, short* __restrict__ Wbf) {
    const int i = blockIdx.x * 256 + threadIdx.x;
    if (i < HID * HID) Wbf[i] = f2bf(W[i]);
}

// ---------------------------------------------------------------------------
// Kernel 2: round-2-validated recurrence (writes d_out).
// ---------------------------------------------------------------------------
template <typename XT>
__global__ __launch_bounds__(256, 1)
void rnn_kernel(const float* __restrict__ W_hh, const XT* __restrict__ xp,
                const float* __restrict__ fc_w, const float* __restrict__ fc_b,
                short* __restrict__ hbuf, unsigned int* __restrict__ bar,
                float* __restrict__ out) {
    extern __shared__ char lds[];
    short* hstage = (short*)(lds + 131072);

    const int bid  = blockIdx.x;
    const int gi   = (bid & 7) + ((bid >> 5) << 3);
    const int gj   = (bid >> 3) & 3;
    const int t    = threadIdx.x;
    const int lane = t & 63;
    const int w    = t >> 6;
    const int row0 = gi * 16;
    const int col0 = gj * 128;

    {
        const int c  = t >> 1;
        const int k0 = (t & 1) * 256;
        const float* src = W_hh + (size_t)(col0 + c) * HID + k0;
        #pragma unroll 4
        for (int u = 0; u < 256; u += 8) {
            f32x4 x0 = *(const f32x4*)(src + u);
            f32x4 x1 = *(const f32x4*)(src + u + 4);
            s16x8 pk;
            pk[0]=f2bf(x0.x); pk[1]=f2bf(x0.y); pk[2]=f2bf(x0.z); pk[3]=f2bf(x0.w);
            pk[4]=f2bf(x1.x); pk[5]=f2bf(x1.y); pk[6]=f2bf(x1.z); pk[7]=f2bf(x1.w);
            int byte = (c * 1024 + (k0 + u) * 2) ^ ((c & 7) << 4);
            *(s16x8*)(lds + byte) = pk;
        }
    }
    __syncthreads();

    const int lr    = lane & 15;
    const int lkb   = (lane >> 4) * 16;
    const int arow  = row0 + lr;
    const int crow0 = row0 + (lane >> 4) * 4;
    unsigned int* mybar = bar + gi;

    int p = 0;
    for (int s = 0; s < SEQ; ++s) {
        f32x4 acc[2];
        #pragma unroll
        for (int nt = 0; nt < 2; ++nt) {
            const int c = col0 + w * 32 + nt * 16 + lr;
            const XT* xs = xp + ((size_t)s * BATCH + crow0) * HID + c;
            #pragma unroll
            for (int r = 0; r < 4; ++r) acc[nt][r] = xp_load(xs + (size_t)r * HID);
        }

        if (s > 0) {
            if (t == 0) {
                const unsigned int target = 4u * (unsigned int)s;
                int guard = 0;
                while (__hip_atomic_load(mybar, __ATOMIC_RELAXED,
                                         __HIP_MEMORY_SCOPE_AGENT) < target) {
                    __builtin_amdgcn_s_sleep(1);
                    if (++guard > (1 << 27)) break;
                }
            }
            __syncthreads();
        }

        const short* hb   = hbuf + (size_t)p * (BATCH * HID);
        const char*  hrow = (const char*)(hb + (size_t)arow * HID);
        s16x8 areg[16];
        #pragma unroll
        for (int kk = 0; kk < 16; ++kk)
            areg[kk] = load_coherent_b128(hrow + kk * 64 + lkb);
        wait_vm0();

        const int cl0 = w * 32 + lr;
        const int cl1 = cl0 + 16;
        #pragma unroll
        for (int kk = 0; kk < 16; ++kk) {
            const int b0b = (cl0 * 1024 + kk * 64 + lkb) ^ ((cl0 & 7) << 4);
            const int b1b = (cl1 * 1024 + kk * 64 + lkb) ^ ((cl1 & 7) << 4);
            const s16x8 b0v = *(const s16x8*)(lds + b0b);
            const s16x8 b1v = *(const s16x8*)(lds + b1b);
            acc[0] = mfma_bf16(areg[kk], b0v, acc[0]);
            acc[1] = mfma_bf16(areg[kk], b1v, acc[1]);
        }

        #pragma unroll
        for (int nt = 0; nt < 2; ++nt) {
            const int cl = w * 32 + nt * 16 + lr;
            #pragma unroll
            for (int r = 0; r < 4; ++r)
                hstage[((crow0 - row0) + r) * 128 + cl] = f2bf(tanhf(acc[nt][r]));
        }
        __syncthreads();

        {
            const int rr = t >> 4, c8 = (t & 15) * 8;
            s16x8 v = *(const s16x8*)(hstage + rr * 128 + c8);
            short* hn = hbuf + (size_t)(p ^ 1) * (BATCH * HID)
                             + (size_t)(row0 + rr) * HID + (col0 + c8);
            store_coherent_b128(hn, v);
        }
        __syncthreads();

        if (t == 0)
            __hip_atomic_fetch_add(mybar, 1u, __ATOMIC_RELAXED,
                                   __HIP_MEMORY_SCOPE_AGENT);
        p ^= 1;
    }

    if (gj == 0) {
        if (t == 0) {
            int guard = 0;
            while (__hip_atomic_load(mybar, __ATOMIC_RELAXED,
                                     __HIP_MEMORY_SCOPE_AGENT) < 4u * SEQ) {
                __builtin_amdgcn_s_sleep(1);
                if (++guard > (1 << 27)) break;
            }
        }
        __syncthreads();

        const int i  = t >> 2;
        const int q  = t & 3;
        const int bl = i >> 2;
        const int o  = i & 3;
        const short* hb = hbuf + (size_t)p * (BATCH * HID)
                               + (size_t)(row0 + bl) * HID + q * 128;
        s16x8 hv[16];
        #pragma unroll
        for (int kk = 0; kk < 16; ++kk)
            hv[kk] = load_coherent_b128((const char*)hb + kk * 16);
        wait_vm0();
        float sum = 0.f;
        #pragma unroll
        for (int kk = 0; kk < 16; ++kk)
            #pragma unroll
            for (int j = 0; j < 8; ++j)
                sum += bf2f(hv[kk][j]) * fc_w[o * HID + q * 128 + kk * 8 + j];
        sum += __shfl_xor(sum, 1);
        sum += __shfl_xor(sum, 2);
        if (q == 0)
            out[(row0 + bl) * OUTD + o] = sum + fc_b[o];
    }
}

// ---------------------------------------------------------------------------
// PROBES (write nothing to d_out; verdict coded in duration):
//   clean(+1ms)  h finite & == validated h
//   nan  (+4ms)  h contains NaN
//   mis  (+8ms)  h finite but mismatched
// MODE 1: 160KB LDS (128 W cols LDS + 2x16KB h), W cols 128..511 from global
//         bf16 per step (NO register W arrays).
// MODE 2: 32KB LDS (h only), ALL W from global bf16 (minimal-LDS control).
// MODE 3: exact round-6 probe (128 W cols LDS + 384 cols in reg arrays,160KB).
// ---------------------------------------------------------------------------
template <int MODE>
__global__ __launch_bounds__(512, 2)
void rnn_probe(const float* __restrict__ W_hh, const short* __restrict__ Wbf,
               const float* __restrict__ xp, const short* __restrict__ href) {
    extern __shared__ char lds[];
    constexpr int WCOLS = (MODE == 2) ? 0 : 128;
    char* Wl = lds;
    char* hB = lds + WCOLS * 1024;

    const int t    = threadIdx.x;
    const int lane = t & 63;
    const int w    = t >> 6;
    const int lr   = lane & 15;
    const int hi   = lane >> 4;
    const int row0 = blockIdx.x * 16;

    if constexpr (WCOLS > 0) {
        const int c  = t >> 2;
        const int k0 = (t & 3) * 128;
        const float* src = W_hh + (size_t)c * HID + k0;
        #pragma unroll 4
        for (int u = 0; u < 128; u += 8) {
            f32x4 x0 = *(const f32x4*)(src + u);
            f32x4 x1 = *(const f32x4*)(src + u + 4);
            s16x8 pk;
            pk[0]=f2bf(x0.x); pk[1]=f2bf(x0.y); pk[2]=f2bf(x0.z); pk[3]=f2bf(x0.w);
            pk[4]=f2bf(x1.x); pk[5]=f2bf(x1.y); pk[6]=f2bf(x1.z); pk[7]=f2bf(x1.w);
            int byte = (c * 1024 + (k0 + u) * 2) ^ ((c & 7) << 4);
            *(s16x8*)(Wl + byte) = pk;
        }
    }
    {
        s16x8 z;
        #pragma unroll
        for (int i = 0; i < 8; ++i) z[i] = 0;
        *(s16x8*)(hB + t * 32) = z;
        *(s16x8*)(hB + 16384 + t * 32) = z;
    }
    s16x8 wr0[16], wr1[16], wr2[16];
    if constexpr (MODE == 3) {
        const float* s0 = W_hh + (size_t)(128 + w * 48 +  0 + lr) * HID + hi * 8;
        const float* s1 = W_hh + (size_t)(128 + w * 48 + 16 + lr) * HID + hi * 8;
        const float* s2 = W_hh + (size_t)(128 + w * 48 + 32 + lr) * HID + hi * 8;
        #pragma unroll
        for (int kk = 0; kk < 16; ++kk) {
            f32x4 a0 = *(const f32x4*)(s0 + kk * 32);
            f32x4 a1 = *(const f32x4*)(s0 + kk * 32 + 4);
            f32x4 b0 = *(const f32x4*)(s1 + kk * 32);
            f32x4 b1 = *(const f32x4*)(s1 + kk * 32 + 4);
            f32x4 c0 = *(const f32x4*)(s2 + kk * 32);
            f32x4 c1 = *(const f32x4*)(s2 + kk * 32 + 4);
            s16x8 p;
            p[0]=f2bf(a0.x); p[1]=f2bf(a0.y); p[2]=f2bf(a0.z); p[3]=f2bf(a0.w);
            p[4]=f2bf(a1.x); p[5]=f2bf(a1.y); p[6]=f2bf(a1.z); p[7]=f2bf(a1.w);
            wr0[kk] = p;
            p[0]=f2bf(b0.x); p[1]=f2bf(b0.y); p[2]=f2bf(b0.z); p[3]=f2bf(b0.w);
            p[4]=f2bf(b1.x); p[5]=f2bf(b1.y); p[6]=f2bf(b1.z); p[7]=f2bf(b1.w);
            wr1[kk] = p;
            p[0]=f2bf(c0.x); p[1]=f2bf(c0.y); p[2]=f2bf(c0.z); p[3]=f2bf(c0.w);
            p[4]=f2bf(c1.x); p[5]=f2bf(c1.y); p[6]=f2bf(c1.z); p[7]=f2bf(c1.w);
            wr2[kk] = p;
        }
    }
    __syncthreads();

    const int crow = hi * 4;
    const int swzL = (lr & 7) << 4;
    // output-column mapping per mode
    auto colOf = [&](int ti) -> int {
        if constexpr (MODE == 2) return w * 64 + ti * 16 + lr;
        else return (ti == 0) ? (w * 16 + lr) : (128 + w * 48 + (ti - 1) * 16 + lr);
    };

    int p = 0;
    #pragma unroll 1
    for (int s = 0; s < SEQ; ++s) {
        const char* hc = hB + p * 16384;
        char*       hn = hB + (p ^ 1) * 16384;

        f32x4 xpv[4];
        {
            const float* xs = xp + ((size_t)s * BATCH + row0 + crow) * HID;
            #pragma unroll
            for (int ti = 0; ti < 4; ++ti) {
                const int c = colOf(ti);
                #pragma unroll
                for (int r = 0; r < 4; ++r)
                    xpv[ti][r] = xs[(size_t)r * HID + c];
            }
        }

        f32x4 acc[4] = {};
        #pragma unroll
        for (int kk = 0; kk < 16; ++kk) {
            const int kb = kk * 64 + hi * 16;
            const s16x8 a = *(const s16x8*)(hc + ((lr * 1024 + kb) ^ swzL));
            if constexpr (MODE == 2) {
                #pragma unroll
                for (int ti = 0; ti < 4; ++ti) {
                    const s16x8 b = *(const s16x8*)(
                        Wbf + (size_t)(w * 64 + ti * 16 + lr) * HID + kk * 32 + hi * 8);
                    acc[ti] = mfma_bf16(a, b, acc[ti]);
                }
            } else if constexpr (MODE == 1) {
                const int colL = w * 16 + lr;
                const s16x8 bl = *(const s16x8*)(Wl + ((colL * 1024 + kb) ^ swzL));
                acc[0] = mfma_bf16(a, bl, acc[0]);
                #pragma unroll
                for (int ti = 1; ti < 4; ++ti) {
                    const s16x8 b = *(const s16x8*)(
                        Wbf + (size_t)(128 + w * 48 + (ti - 1) * 16 + lr) * HID + kk * 32 + hi * 8);
                    acc[ti] = mfma_bf16(a, b, acc[ti]);
                }
            } else {
                const int colL = w * 16 + lr;
                const s16x8 bl = *(const s16x8*)(Wl + ((colL * 1024 + kb) ^ swzL));
                acc[0] = mfma_bf16(a, bl,      acc[0]);
                acc[1] = mfma_bf16(a, wr0[kk], acc[1]);
                acc[2] = mfma_bf16(a, wr1[kk], acc[2]);
                acc[3] = mfma_bf16(a, wr2[kk], acc[3]);
            }
        }

        #pragma unroll
        for (int ti = 0; ti < 4; ++ti) {
            const int c = colOf(ti);
            #pragma unroll
            for (int r = 0; r < 4; ++r) {
                const float hv = tanhf(acc[ti][r] + xpv[ti][r]);
                const int rr = crow + r;
                *(short*)(hn + ((rr * 1024 + c * 2) ^ ((rr & 7) << 4))) = f2bf(hv);
            }
        }
        __syncthreads();
        p ^= 1;
    }

    // ---- verdict (final h in buffer 0; flg region = buffer 1) ----
    {
        int* flg = (int*)(hB + 16384);
        if (t == 0) { flg[0] = 0; flg[1] = 0; }
        __syncthreads();
        const char* hf = hB;
        const int rr = t >> 5;               // 0..15
        const int c0 = (t & 31) * 16;        // 16 cols/thread
        const int fswz = (rr & 7) << 4;
        const short* hr = href + (size_t)(row0 + rr) * HID + c0;
        s16x8 r0 = load_coherent_b128(hr);
        s16x8 r1 = load_coherent_b128(hr + 8);
        wait_vm0();
        int bad_nan = 0, bad_mis = 0;
        #pragma unroll
        for (int j = 0; j < 16; ++j) {
            const int c = c0 + j;
            const float a = bf2f(*(const short*)(hf + ((rr * 1024 + c * 2) ^ fswz)));
            const float b = bf2f((j < 8) ? r0[j] : r1[j - 8]);
            if (!(a == a)) bad_nan = 1;
            else if (!(fabsf(a - b) <= 0.05f)) bad_mis = 1;
        }
        if (bad_nan) flg[0] = 1;
        if (bad_mis) flg[1] = 1;
        __syncthreads();
        const int units = flg[0] ? 4 : (flg[1] ? 8 : 1);
        spin_units(units);
    }
}

// ---------------------------------------------------------------------------
extern "C" void kernel_launch(void* const* d_in, const int* in_sizes, int n_in,
                              void* d_out, int out_size, void* d_ws, size_t ws_size,
                              hipStream_t stream) {
    (void)in_sizes; (void)n_in; (void)out_size;
    const int*   text = (const int*)  d_in[0];
    const float* emb  = (const float*)d_in[1];
    const float* W_ih = (const float*)d_in[2];
    const float* W_hh = (const float*)d_in[3];
    const float* b_ih = (const float*)d_in[4];
    const float* b_hh = (const float*)d_in[5];
    const float* fc_w = (const float*)d_in[6];
    const float* fc_b = (const float*)d_in[7];
    float* out = (float*)d_out;

    char* ws = (char*)d_ws;
    short*        hbuf = (short*)ws;                        // 512 KB
    unsigned int* bar  = (unsigned int*)(ws + (512 << 10));
    char*         xpbf = ws + (1 << 20);

    const size_t base  = (size_t)1 << 20;
    const size_t xp_e  = (size_t)SEQ * BATCH * HID;
    const size_t wbf_off = base + xp_e * 4;
    const bool probe_ok = ws_size >= wbf_off + (size_t)HID * HID * 2;
    const bool use_f32  = ws_size >= base + xp_e * 4;
    const bool use_bf16 = !use_f32 && ws_size >= base + xp_e * 2;

    hipMemsetAsync(ws, 0, (512 << 10) + 4096, stream);

    if (use_f32) {
        hipFuncSetAttribute(reinterpret_cast<const void*>(&xproj_kernel<float>),
                            hipFuncAttributeMaxDynamicSharedMemorySize, 131072);
        hipFuncSetAttribute(reinterpret_cast<const void*>(&rnn_kernel<float>),
                            hipFuncAttributeMaxDynamicSharedMemorySize, 135168);
        xproj_kernel<float><<<dim3(1024, 4, 1), 512, 131072, stream>>>(
            text, emb, W_ih, b_ih, b_hh, (float*)xpbf);
        rnn_kernel<float><<<64, 256, 135168, stream>>>(
            W_hh, (const float*)xpbf, fc_w, fc_b, hbuf, bar, out);
        if (probe_ok) {
            short* Wbf = (short*)(ws + wbf_off);
            wprep_kernel<<<1024, 256, 0, stream>>>(W_hh, Wbf);
            hipFuncSetAttribute(reinterpret_cast<const void*>(&rnn_probe<1>),
                                hipFuncAttributeMaxDynamicSharedMemorySize, 163840);
            hipFuncSetAttribute(reinterpret_cast<const void*>(&rnn_probe<2>),
                                hipFuncAttributeMaxDynamicSharedMemorySize, 32768);
            hipFuncSetAttribute(reinterpret_cast<const void*>(&rnn_probe<3>),
                                hipFuncAttributeMaxDynamicSharedMemorySize, 163840);
            rnn_probe<1><<<16, 512, 163840, stream>>>(
                W_hh, Wbf, (const float*)xpbf, hbuf);
            rnn_probe<2><<<16, 512, 32768, stream>>>(
                W_hh, Wbf, (const float*)xpbf, hbuf);
            rnn_probe<3><<<16, 512, 163840, stream>>>(
                W_hh, Wbf, (const float*)xpbf, hbuf);
        }
    } else if (use_bf16) {
        hipFuncSetAttribute(reinterpret_cast<const void*>(&xproj_kernel<short>),
                            hipFuncAttributeMaxDynamicSharedMemorySize, 131072);
        hipFuncSetAttribute(reinterpret_cast<const void*>(&rnn_kernel<short>),
                            hipFuncAttributeMaxDynamicSharedMemorySize, 135168);
        xproj_kernel<short><<<dim3(1024, 4, 1), 512, 131072, stream>>>(
            text, emb, W_ih, b_ih, b_hh, (short*)xpbf);
        rnn_kernel<short><<<64, 256, 135168, stream>>>(
            W_hh, (const short*)xpbf, fc_w, fc_b, hbuf, bar, out);
    }
}